// Round 8
// baseline (335.261 us; speedup 1.0000x reference)
//
#include <hip/hip_runtime.h>
#include <cstdint>
#include <cstddef>

using half8  = __attribute__((ext_vector_type(8))) _Float16;
using half4  = __attribute__((ext_vector_type(4))) _Float16;
using float4v = __attribute__((ext_vector_type(4))) float;

#define CD 1024
#define M2 (1024 * 1024)

// async global->LDS, 16B per lane, wave-uniform LDS base + lane*16 dest
#define GLD16(gp, lp)                                                          \
    __builtin_amdgcn_global_load_lds(                                          \
        (const __attribute__((address_space(1))) void*)(gp),                   \
        (__attribute__((address_space(3))) void*)(lp), 16, 0, 0)

// ---------------------------------------------------------------------------
// Weight prep: f32 -> f16, stack Wf/Wg/Wh into one (3C x C), stack biases.
// ---------------------------------------------------------------------------
__global__ void prep_weights(const float* __restrict__ Wf, const float* __restrict__ Wg,
                             const float* __restrict__ Wh, const float* __restrict__ Wc,
                             const float* __restrict__ bf, const float* __restrict__ bg,
                             const float* __restrict__ bh,
                             _Float16* __restrict__ Wfgh, _Float16* __restrict__ WcH,
                             float* __restrict__ bstack) {
    int idx = blockIdx.x * 256 + threadIdx.x;
    if (idx < 3 * M2) {
        const float* s = idx < M2 ? Wf : (idx < 2 * M2 ? Wg : Wh);
        int off = idx & (M2 - 1);
        Wfgh[idx] = (_Float16)s[off];
    } else if (idx < 4 * M2) {
        WcH[idx - 3 * M2] = (_Float16)Wc[idx - 3 * M2];
    } else if (idx < 4 * M2 + 3 * CD) {
        int j = idx - 4 * M2;
        const float* s = j < CD ? bf : (j < 2 * CD ? bg : bh);
        bstack[j] = s[j & (CD - 1)];
    }
}

// ---------------------------------------------------------------------------
// Per-batch transpose: x[b][k][n] (f32) -> xT[z][n][k] (f16)
// ---------------------------------------------------------------------------
__global__ void transpose_x(const float* __restrict__ x, _Float16* __restrict__ xT, int b0) {
    __shared__ float tile[32][33];
    int z = blockIdx.z;
    const float* xb = x + (size_t)(b0 + z) * M2;
    _Float16* xTb = xT + (size_t)z * M2;
    int n0 = blockIdx.x * 32, k0 = blockIdx.y * 32;
    int tx = threadIdx.x, ty = threadIdx.y;  // 32 x 8
#pragma unroll
    for (int i = 0; i < 4; i++)
        tile[ty + i * 8][tx] = xb[(size_t)(k0 + ty + i * 8) * CD + n0 + tx];
    __syncthreads();
#pragma unroll
    for (int i = 0; i < 4; i++)
        xTb[(size_t)(n0 + ty + i * 8) * CD + k0 + tx] = (_Float16)tile[tx][ty + i * 8];
}

// ---------------------------------------------------------------------------
// Row softmax over ST (f32, rows are fixed d, reduce over c) -> attnT (f16)
// ---------------------------------------------------------------------------
__global__ __launch_bounds__(256) void softmax_col(const float* __restrict__ ST,
                                                   _Float16* __restrict__ attnT) {
    int d = blockIdx.x, z = blockIdx.y;
    const float* row = ST + ((size_t)z * CD + d) * CD;
    _Float16* orow = attnT + ((size_t)z * CD + d) * CD;
    int t = threadIdx.x;
    float4v v = *(const float4v*)(row + t * 4);
    float mx = fmaxf(fmaxf(v[0], v[1]), fmaxf(v[2], v[3]));
#pragma unroll
    for (int o = 32; o > 0; o >>= 1) mx = fmaxf(mx, __shfl_xor(mx, o));
    __shared__ float redm[4], reds[4];
    int wave = t >> 6, lane = t & 63;
    if (lane == 0) redm[wave] = mx;
    __syncthreads();
    mx = fmaxf(fmaxf(redm[0], redm[1]), fmaxf(redm[2], redm[3]));
    float e[4];
    float s = 0.f;
#pragma unroll
    for (int i = 0; i < 4; i++) {
        e[i] = __expf(v[i] - mx);
        s += e[i];
    }
#pragma unroll
    for (int o = 32; o > 0; o >>= 1) s += __shfl_xor(s, o);
    if (lane == 0) reds[wave] = s;
    __syncthreads();
    s = reds[0] + reds[1] + reds[2] + reds[3];
    float inv = 1.0f / s;
    half4 ov;
#pragma unroll
    for (int i = 0; i < 4; i++) ov[i] = (_Float16)(e[i] * inv);
    *(half4*)(orow + t * 4) = ov;
}

// ---------------------------------------------------------------------------
// NT GEMM, 256x256, 4-buffer pipeline, 1 barrier/tile, REGISTER PREFETCH:
// reads(t+1) issue under MFMA(t) (frag double-buffer, compile-time sets).
// C[m][n] = sum_k A[m][k]*B[n][k], K=1024, BK=32, 32 K-tiles.
// 8 waves (2Mx4N), per-wave output 128x64 (acc[8][4]), 16x16x32 f16 MFMA.
// LDS: 4 K-tile buffers x (A 256x32 + B 256x32) f16 = 128 KiB; 1 block/CU.
//
// Per-iter ledger (4 gload_lds/tile/thread, in-order vmcnt retire):
//   top of t: regs hold frags(t) [read last iter]; outstanding {t+1,t+2}=8.
//   vmcnt(4)  -> MY tile t+1 landed
//   s_barrier -> ALL waves: t+1 published; all issued MFMA(t-1), so all
//                reads of buf[(t-1)&3] are consumed
//   STAGE(t+3 -> buf[(t+3)&3] = buf[(t-1)&3])   (write-safe by barrier)
//   READS(frags(t+1) <- buf[(t+1)&3])           (read-safe: vmcnt+barrier;
//                                                buffer != stage buffer, +2 mod 4)
//   32x MFMA on frags(t) — no lgkm wait (operands 1 iter old); ds_read
//   latency + LDS BW of reads(t+1) hide under the MFMA burst.
// Prologue: stage {0,1,2}; vmcnt(8); barrier; reads(0).
// Tail: t=29 vmcnt(4), t=30 vmcnt(0), t=31 MFMA-only.
// Swizzle (r3-verified conflict-free; LDS[r][c8]=global[c8^(((r&15)>>1)&3)]):
//   stage source col = ((lane&3) ^ ((lane>>3)&3))*8, linear LDS dest;
//   read col = kq ^ (((rl>>1)&3)<<3)  [all frag-read rows have row&15==rl].
// ---------------------------------------------------------------------------
enum { EP_F16B = 0, EP_F32 = 1, EP_F16 = 2, EP_FIN = 3 };

#define STAGE_A(T, BUF)                                                        \
    GLD16(gA0 + (size_t)(T) * 32, &As[BUF][wv * 16][0]);                       \
    GLD16(gA1 + (size_t)(T) * 32, &As[BUF][128 + wv * 16][0]);
#define STAGE_B(T, BUF)                                                        \
    GLD16(gB0 + (size_t)(T) * 32, &Bs[BUF][wv * 16][0]);                       \
    GLD16(gB1 + (size_t)(T) * 32, &Bs[BUF][128 + wv * 16][0]);

#define READS(SET, BUF)                                                        \
    _Pragma("unroll") for (int m = 0; m < 8; m++)                              \
        a##SET[m] = *(const half8*)&As[BUF][wr * 128 + m * 16 + rl][kqa];      \
    _Pragma("unroll") for (int n = 0; n < 4; n++)                              \
        b##SET[n] = *(const half8*)&Bs[BUF][wc * 64 + n * 16 + rl][kqa];

#define MFMA32(SET)                                                            \
    __builtin_amdgcn_s_setprio(1);                                             \
    _Pragma("unroll") for (int m = 0; m < 8; m++)                              \
        _Pragma("unroll") for (int n = 0; n < 4; n++)                          \
            acc[m][n] = __builtin_amdgcn_mfma_f32_16x16x32_f16(                \
                a##SET[m], b##SET[n], acc[m][n], 0, 0, 0);                     \
    __builtin_amdgcn_s_setprio(0);

// SETC: frags for MFMA (tile t). SETN/RBUF: frag set + LDS buf for reads(t+1).
#define ITER(SETC, SETN, RBUF, DOSTAGE, STT, STBUF, DOVM, VMSTR, DOREAD, DOBAR)\
    {                                                                          \
        if (DOVM) {                                                            \
            asm volatile("s_waitcnt " VMSTR ::: "memory");                     \
            __builtin_amdgcn_sched_barrier(0);                                 \
        }                                                                      \
        if (DOBAR) __builtin_amdgcn_s_barrier();                               \
        if (DOSTAGE) { STAGE_A(STT, STBUF) STAGE_B(STT, STBUF) }               \
        if (DOREAD) { READS(SETN, RBUF) }                                      \
        MFMA32(SETC)                                                           \
    }

template <int EPI>
__global__ __launch_bounds__(512, 2) void gemm_nt(
    const _Float16* __restrict__ A, int64_t sA, const _Float16* __restrict__ B, int64_t sB,
    void* __restrict__ Cp, int64_t sC, const float* __restrict__ bias,
    const float* __restrict__ bc, const float* __restrict__ gamma,
    const float* __restrict__ beta, const float* __restrict__ rmean,
    const float* __restrict__ rvar, const float* __restrict__ xres) {
    __shared__ __align__(16) _Float16 As[4][256][32];
    __shared__ __align__(16) _Float16 Bs[4][256][32];
    int z = blockIdx.z;
    const _Float16* Ab = A + (size_t)z * sA;
    const _Float16* Bb = B + (size_t)z * sB;
    int row0 = blockIdx.y * 256, col0 = blockIdx.x * 256;
    int tid = threadIdx.x, lane = tid & 63, wv = tid >> 6;
    int wr = wv >> 2, wc = wv & 3;

    // Staging: issue i covers rows [i*128 + wv*16, +16); lane l -> row + l/4,
    // source col pre-swizzled (LDS dest stays linear).
    const int srow = wv * 16 + (lane >> 2);
    const int scol = ((lane & 3) ^ ((lane >> 3) & 3)) * 8;
    const _Float16* gA0 = Ab + (size_t)(row0 + srow) * 1024 + scol;
    const _Float16* gA1 = gA0 + (size_t)128 * 1024;
    const _Float16* gB0 = Bb + (size_t)(col0 + srow) * 1024 + scol;
    const _Float16* gB1 = gB0 + (size_t)128 * 1024;

    const int rl = lane & 15;
    const int kq = (lane >> 4) * 8;
    const int kqa = kq ^ (((rl >> 1) & 3) << 3);  // read-side swizzle

    float4v acc[8][4] = {};
    half8 a0[8], b0[4], a1[8], b1[4];

    // Prologue: stage tiles 0,1,2; wait tile 0; publish; pre-read frags(0).
    STAGE_A(0, 0) STAGE_B(0, 0)
    STAGE_A(1, 1) STAGE_B(1, 1)
    STAGE_A(2, 2) STAGE_B(2, 2)
    asm volatile("s_waitcnt vmcnt(8)" ::: "memory");
    __builtin_amdgcn_sched_barrier(0);
    __builtin_amdgcn_s_barrier();
    READS(0, 0)

#pragma unroll 1
    for (int g = 0; g < 7; ++g) {  // tiles t..t+3, t=4g; stages t+3..t+6
        int t = g * 4;
        ITER(0, 1, 1, 1, t + 3, 3, 1, "vmcnt(4)", 1, 1)  // t%4==0
        ITER(1, 0, 2, 1, t + 4, 0, 1, "vmcnt(4)", 1, 1)  // t%4==1
        ITER(0, 1, 3, 1, t + 5, 1, 1, "vmcnt(4)", 1, 1)  // t%4==2
        ITER(1, 0, 0, 1, t + 6, 2, 1, "vmcnt(4)", 1, 1)  // t%4==3
    }
    // Tail tiles 28..31 (t=28 stages tile 31).
    ITER(0, 1, 1, 1, 31, 3, 1, "vmcnt(4)", 1, 1)  // t=28
    ITER(1, 0, 2, 0, 0, 0, 1, "vmcnt(4)", 1, 1)   // t=29
    ITER(0, 1, 3, 0, 0, 0, 1, "vmcnt(0)", 1, 1)   // t=30
    ITER(1, 0, 0, 0, 0, 0, 0, "", 0, 0)           // t=31: MFMA only

    // Epilogue. C/D layout: col = lane&15, row = (lane>>4)*4 + reg  [m89]
#pragma unroll
    for (int m = 0; m < 8; m++) {
#pragma unroll
        for (int r = 0; r < 4; r++) {
            int row = row0 + wr * 128 + m * 16 + ((lane >> 4) << 2) + r;
            float add0 = 0.f, mu = 0.f, invs = 1.f, bet = 0.f;
            if constexpr (EPI == EP_F16B) add0 = bias[row];
            if constexpr (EPI == EP_FIN) {
                add0 = bc[row];
                mu = rmean[row];
                invs = gamma[row] * rsqrtf(rvar[row] + 1e-5f);
                bet = beta[row];
            }
#pragma unroll
            for (int n = 0; n < 4; n++) {
                int col = col0 + wc * 64 + n * 16 + (lane & 15);
                float v = acc[m][n][r];
                if constexpr (EPI == EP_F16B) {
                    ((_Float16*)Cp)[(size_t)z * sC + (size_t)row * 1024 + col] = (_Float16)(v + add0);
                } else if constexpr (EPI == EP_F32) {
                    ((float*)Cp)[(size_t)z * sC + (size_t)row * 1024 + col] = v;
                } else if constexpr (EPI == EP_F16) {
                    ((_Float16*)Cp)[(size_t)z * sC + (size_t)row * 1024 + col] = (_Float16)v;
                } else {
                    v += add0;
                    v = v >= 0.f ? v : 0.01f * v;
                    v = (v - mu) * invs + bet;
                    v += xres[(size_t)z * M2 + (size_t)row * 1024 + col];
                    ((float*)Cp)[(size_t)z * sC + (size_t)row * 1024 + col] = v;
                }
            }
        }
    }
}

// ---------------------------------------------------------------------------
extern "C" void kernel_launch(void* const* d_in, const int* in_sizes, int n_in,
                              void* d_out, int out_size, void* d_ws, size_t ws_size,
                              hipStream_t stream) {
    const float* x = (const float*)d_in[0];
    const float* Wf = (const float*)d_in[1];
    const float* bf = (const float*)d_in[2];
    const float* Wg = (const float*)d_in[3];
    const float* bg = (const float*)d_in[4];
    const float* Wh = (const float*)d_in[5];
    const float* bh = (const float*)d_in[6];
    const float* Wc = (const float*)d_in[7];
    const float* bc = (const float*)d_in[8];
    const float* gamma = (const float*)d_in[9];
    const float* beta = (const float*)d_in[10];
    const float* rmean = (const float*)d_in[11];
    const float* rvar = (const float*)d_in[12];

    // Fixed ws region: Wfgh f16 (6MB) + Wc f16 (2MB) + bias stack
    char* p = (char*)d_ws;
    _Float16* Wfgh = (_Float16*)p;
    p += (size_t)3 * M2 * 2;
    _Float16* WcH = (_Float16*)p;
    p += (size_t)M2 * 2;
    float* bstack = (float*)p;
    p += (size_t)3 * CD * 4;
    size_t fixed = (size_t)(p - (char*)d_ws);
    fixed = (fixed + 255) & ~(size_t)255;

    // Per-batch region: xT f16 (2MB, reused as attnT) + FGH f16 (6MB) +
    // ST f32 (4MB, reused as hfgT f16). 12 MiB per batch.
    size_t perB = (size_t)2 * M2 + (size_t)6 * M2 + (size_t)4 * M2;
    int nb = 16;
    while (nb > 1 && fixed + (size_t)nb * perB > ws_size) nb >>= 1;

    {
        int total = 4 * M2 + 3 * CD;
        prep_weights<<<dim3((total + 255) / 256), dim3(256), 0, stream>>>(
            Wf, Wg, Wh, Wc, bf, bg, bh, Wfgh, WcH, bstack);
    }

    for (int b0 = 0; b0 < 16; b0 += nb) {
        char* q = (char*)d_ws + fixed;
        _Float16* xT = (_Float16*)q;
        _Float16* FGH = (_Float16*)(q + (size_t)nb * 2 * M2);
        float* ST = (float*)(q + (size_t)nb * 8 * M2);
        _Float16* attnT = xT;          // xT dead after GEMM1
        _Float16* hfgT = (_Float16*)ST;  // ST dead after softmax

        // xT[z][n][k] = x[b0+z][k][n]
        transpose_x<<<dim3(32, 32, nb), dim3(32, 8), 0, stream>>>(x, xT, b0);
        // FGH[z] (3072 x 1024) = Wfgh (3072x1024) . xT[z]^T  + bias
        gemm_nt<EP_F16B><<<dim3(4, 12, nb), dim3(512), 0, stream>>>(
            Wfgh, 0, xT, M2, FGH, (int64_t)3 * M2, bstack,
            nullptr, nullptr, nullptr, nullptr, nullptr, nullptr);
        // ST[z][d][c] = sum_n G[d][n] F[c][n]
        gemm_nt<EP_F32><<<dim3(4, 4, nb), dim3(512), 0, stream>>>(
            FGH + M2, (int64_t)3 * M2, FGH, (int64_t)3 * M2, ST, M2,
            nullptr, nullptr, nullptr, nullptr, nullptr, nullptr, nullptr);
        // attnT[z][d][c] = softmax over c of ST[z][d][:]
        softmax_col<<<dim3(1024, nb), dim3(256), 0, stream>>>(ST, attnT);
        // hfgT[z][d][c] = sum_n attnT[d][n] H[c][n]
        gemm_nt<EP_F16><<<dim3(4, 4, nb), dim3(512), 0, stream>>>(
            attnT, M2, FGH + 2 * M2, (int64_t)3 * M2, hfgT, M2,
            nullptr, nullptr, nullptr, nullptr, nullptr, nullptr, nullptr);
        // out[b][o][d] = BN(leaky(Wc . hfgT^T + bc)) + x
        gemm_nt<EP_FIN><<<dim3(4, 4, nb), dim3(512), 0, stream>>>(
            WcH, 0, hfgT, M2, (float*)d_out + (size_t)b0 * M2, M2,
            nullptr, bc, gamma, beta, rmean, rvar, x + (size_t)b0 * M2);
    }
}

// Round 9
// 290.735 us; speedup vs baseline: 1.1531x; 1.1531x over previous
//
#include <hip/hip_runtime.h>
#include <cstdint>
#include <cstddef>

using half8  = __attribute__((ext_vector_type(8))) _Float16;
using half4  = __attribute__((ext_vector_type(4))) _Float16;
using float4v = __attribute__((ext_vector_type(4))) float;

#define CD 1024
#define M2 (1024 * 1024)

// async global->LDS, 16B per lane, wave-uniform LDS base + lane*16 dest
#define GLD16(gp, lp)                                                          \
    __builtin_amdgcn_global_load_lds(                                          \
        (const __attribute__((address_space(1))) void*)(gp),                   \
        (__attribute__((address_space(3))) void*)(lp), 16, 0, 0)

// ---------------------------------------------------------------------------
// Weight prep: f32 -> f16, stack Wf/Wg/Wh into one (3C x C), stack biases.
// (Wh slot of Wfgh is later overwritten by Wch = Wc.Wh; bh slot of bstack is
//  later overwritten by bch = Wc.bh — stream-ordered.)
// ---------------------------------------------------------------------------
__global__ void prep_weights(const float* __restrict__ Wf, const float* __restrict__ Wg,
                             const float* __restrict__ Wh, const float* __restrict__ Wc,
                             const float* __restrict__ bf, const float* __restrict__ bg,
                             const float* __restrict__ bh,
                             _Float16* __restrict__ Wfgh, _Float16* __restrict__ WcH,
                             float* __restrict__ bstack) {
    int idx = blockIdx.x * 256 + threadIdx.x;
    if (idx < 3 * M2) {
        const float* s = idx < M2 ? Wf : (idx < 2 * M2 ? Wg : Wh);
        int off = idx & (M2 - 1);
        Wfgh[idx] = (_Float16)s[off];
    } else if (idx < 4 * M2) {
        WcH[idx - 3 * M2] = (_Float16)Wc[idx - 3 * M2];
    } else if (idx < 4 * M2 + 3 * CD) {
        int j = idx - 4 * M2;
        const float* s = j < CD ? bf : (j < 2 * CD ? bg : bh);
        bstack[j] = s[j & (CD - 1)];
    }
}

// ---------------------------------------------------------------------------
// Tiled transpose: src[b0+z][k][n] (f32) -> dst[z][n][k] (f16)
// Also reused for Wh^T (grid z=1, b0=0).
// ---------------------------------------------------------------------------
__global__ void transpose_x(const float* __restrict__ x, _Float16* __restrict__ xT, int b0) {
    __shared__ float tile[32][33];
    int z = blockIdx.z;
    const float* xb = x + (size_t)(b0 + z) * M2;
    _Float16* xTb = xT + (size_t)z * M2;
    int n0 = blockIdx.x * 32, k0 = blockIdx.y * 32;
    int tx = threadIdx.x, ty = threadIdx.y;  // 32 x 8
#pragma unroll
    for (int i = 0; i < 4; i++)
        tile[ty + i * 8][tx] = xb[(size_t)(k0 + ty + i * 8) * CD + n0 + tx];
    __syncthreads();
#pragma unroll
    for (int i = 0; i < 4; i++)
        xTb[(size_t)(n0 + ty + i * 8) * CD + k0 + tx] = (_Float16)tile[tx][ty + i * 8];
}

// ---------------------------------------------------------------------------
// bch[o] = sum_c Wc[o][c] * bh[c]   (one wave per o-row, 4 rows/block)
// ---------------------------------------------------------------------------
__global__ __launch_bounds__(256) void gemv_bch(const float* __restrict__ Wc,
                                                const float* __restrict__ bh,
                                                float* __restrict__ bch) {
    int o = blockIdx.x * 4 + (threadIdx.x >> 6);
    int lane = threadIdx.x & 63;
    float s = 0.f;
    for (int c = lane; c < CD; c += 64) s += Wc[(size_t)o * CD + c] * bh[c];
#pragma unroll
    for (int off = 32; off > 0; off >>= 1) s += __shfl_xor(s, off);
    if (lane == 0) bch[o] = s;
}

// ---------------------------------------------------------------------------
// One-shot 1024^3 NT GEMM (m97 structure, r2-verified): C = A.B^T, f16 out.
// 128x128 tile, BK=32, 4 waves. Used once for Wch = WcH . WhT^T.
// ---------------------------------------------------------------------------
__global__ __launch_bounds__(256) void gemm128(const _Float16* __restrict__ A,
                                               const _Float16* __restrict__ B,
                                               _Float16* __restrict__ C) {
    __shared__ __align__(16) _Float16 As[128][32];
    __shared__ __align__(16) _Float16 Bs[128][32];
    int row0 = blockIdx.y * 128, col0 = blockIdx.x * 128;
    int tid = threadIdx.x, lane = tid & 63, wave = tid >> 6;
    int wr = wave >> 1, wc = wave & 1;
    const int srow = lane >> 2;
    const int scol = (lane & 3) * 8;
    const size_t gA0 = (size_t)(row0 + wave * 16 + srow) * 1024 + scol;
    const size_t gA1 = gA0 + (size_t)64 * 1024;
    const size_t gB0 = (size_t)(col0 + wave * 16 + srow) * 1024 + scol;
    const size_t gB1 = gB0 + (size_t)64 * 1024;
    _Float16* ldsA0 = &As[wave * 16][0];
    _Float16* ldsA1 = &As[64 + wave * 16][0];
    _Float16* ldsB0 = &Bs[wave * 16][0];
    _Float16* ldsB1 = &Bs[64 + wave * 16][0];
    float4v acc[4][4] = {};
    const int kq = (lane >> 4) * 8, rl = lane & 15;
    for (int kt = 0; kt < 1024; kt += 32) {
        GLD16(A + gA0 + kt, ldsA0);
        GLD16(A + gA1 + kt, ldsA1);
        GLD16(B + gB0 + kt, ldsB0);
        GLD16(B + gB1 + kt, ldsB1);
        __syncthreads();
        half8 af[4], bfr[4];
#pragma unroll
        for (int m = 0; m < 4; m++) af[m] = *(const half8*)(&As[wr * 64 + m * 16 + rl][kq]);
#pragma unroll
        for (int n = 0; n < 4; n++) bfr[n] = *(const half8*)(&Bs[wc * 64 + n * 16 + rl][kq]);
#pragma unroll
        for (int m = 0; m < 4; m++)
#pragma unroll
            for (int n = 0; n < 4; n++)
                acc[m][n] = __builtin_amdgcn_mfma_f32_16x16x32_f16(af[m], bfr[n], acc[m][n], 0, 0, 0);
        __syncthreads();
    }
#pragma unroll
    for (int m = 0; m < 4; m++)
#pragma unroll
        for (int r = 0; r < 4; r++) {
            int row = row0 + wr * 64 + m * 16 + ((lane >> 4) << 2) + r;
#pragma unroll
            for (int n = 0; n < 4; n++) {
                int col = col0 + wc * 64 + n * 16 + (lane & 15);
                C[(size_t)row * 1024 + col] = (_Float16)acc[m][n][r];
            }
        }
}

// ---------------------------------------------------------------------------
// Row softmax over ST (f32, rows are fixed d, reduce over c) -> attnT (f16)
// ---------------------------------------------------------------------------
__global__ __launch_bounds__(256) void softmax_col(const float* __restrict__ ST,
                                                   _Float16* __restrict__ attnT) {
    int d = blockIdx.x, z = blockIdx.y;
    const float* row = ST + ((size_t)z * CD + d) * CD;
    _Float16* orow = attnT + ((size_t)z * CD + d) * CD;
    int t = threadIdx.x;
    float4v v = *(const float4v*)(row + t * 4);
    float mx = fmaxf(fmaxf(v[0], v[1]), fmaxf(v[2], v[3]));
#pragma unroll
    for (int o = 32; o > 0; o >>= 1) mx = fmaxf(mx, __shfl_xor(mx, o));
    __shared__ float redm[4], reds[4];
    int wave = t >> 6, lane = t & 63;
    if (lane == 0) redm[wave] = mx;
    __syncthreads();
    mx = fmaxf(fmaxf(redm[0], redm[1]), fmaxf(redm[2], redm[3]));
    float e[4];
    float s = 0.f;
#pragma unroll
    for (int i = 0; i < 4; i++) {
        e[i] = __expf(v[i] - mx);
        s += e[i];
    }
#pragma unroll
    for (int o = 32; o > 0; o >>= 1) s += __shfl_xor(s, o);
    if (lane == 0) reds[wave] = s;
    __syncthreads();
    s = reds[0] + reds[1] + reds[2] + reds[3];
    float inv = 1.0f / s;
    half4 ov;
#pragma unroll
    for (int i = 0; i < 4; i++) ov[i] = (_Float16)(e[i] * inv);
    *(half4*)(orow + t * 4) = ov;
}

// ---------------------------------------------------------------------------
// NT GEMM, 256x256, 4-buffer 3-deep pipeline, ONE barrier per K-tile
// (round-7 structure — best measured, 851 TF).
// C[m][n] = sum_k A[m][k]*B[n][k], K=1024, BK=32, 32 K-tiles.
// 8 waves (2Mx4N), per-wave output 128x64 (acc[8][4]), 16x16x32 f16 MFMA.
// LDS: 4 K-tile buffers x (A 256x32 + B 256x32) f16 = 128 KiB; 1 block/CU.
// Per-tile: vmcnt(8) [tile t landed] -> barrier [published; buf t-1 free] ->
// 12 ds_reads -> STAGE(t+3 -> buf[(t-1)&3]) -> 32 MFMA (counted lgkm by
// compiler). Tail vmcnt(8),(8),(4),(0). Prologue stages {0,1,2}.
// Swizzle (r3-verified conflict-free): stage source col =
// ((lane&3)^((lane>>3)&3))*8 (linear LDS dest); read col = kq^(((rl>>1)&3)<<3).
// ---------------------------------------------------------------------------
enum { EP_F16B = 0, EP_F32 = 1, EP_F16 = 2, EP_FIN = 3 };

#define STAGE_A(T, BUF)                                                        \
    GLD16(gA0 + (size_t)(T) * 32, &As[BUF][wv * 16][0]);                       \
    GLD16(gA1 + (size_t)(T) * 32, &As[BUF][128 + wv * 16][0]);
#define STAGE_B(T, BUF)                                                        \
    GLD16(gB0 + (size_t)(T) * 32, &Bs[BUF][wv * 16][0]);                       \
    GLD16(gB1 + (size_t)(T) * 32, &Bs[BUF][128 + wv * 16][0]);

#define TILE(BUF, DOSTAGE, STT, STBUF, VMSTR)                                  \
    {                                                                          \
        asm volatile("s_waitcnt " VMSTR ::: "memory");                         \
        __builtin_amdgcn_sched_barrier(0);                                     \
        __builtin_amdgcn_s_barrier();                                          \
        _Pragma("unroll") for (int m = 0; m < 4; m++)                          \
            a[m] = *(const half8*)&As[BUF][wr * 128 + m * 16 + rl][kqa];       \
        _Pragma("unroll") for (int n = 0; n < 4; n++)                          \
            b[n] = *(const half8*)&Bs[BUF][wc * 64 + n * 16 + rl][kqa];        \
        _Pragma("unroll") for (int m = 4; m < 8; m++)                          \
            a[m] = *(const half8*)&As[BUF][wr * 128 + m * 16 + rl][kqa];       \
        if (DOSTAGE) { STAGE_A(STT, STBUF) STAGE_B(STT, STBUF) }               \
        __builtin_amdgcn_sched_barrier(0);                                     \
        __builtin_amdgcn_s_setprio(1);                                         \
        _Pragma("unroll") for (int m = 0; m < 8; m++)                          \
            _Pragma("unroll") for (int n = 0; n < 4; n++)                      \
                acc[m][n] = __builtin_amdgcn_mfma_f32_16x16x32_f16(            \
                    a[m], b[n], acc[m][n], 0, 0, 0);                           \
        __builtin_amdgcn_s_setprio(0);                                         \
    }

template <int EPI>
__global__ __launch_bounds__(512, 2) void gemm_nt(
    const _Float16* __restrict__ A, int64_t sA, const _Float16* __restrict__ B, int64_t sB,
    void* __restrict__ Cp, int64_t sC, const float* __restrict__ bias,
    const float* __restrict__ bc, const float* __restrict__ gamma,
    const float* __restrict__ beta, const float* __restrict__ rmean,
    const float* __restrict__ rvar, const float* __restrict__ xres) {
    __shared__ __align__(16) _Float16 As[4][256][32];
    __shared__ __align__(16) _Float16 Bs[4][256][32];
    int z = blockIdx.z;
    const _Float16* Ab = A + (size_t)z * sA;
    const _Float16* Bb = B + (size_t)z * sB;
    int row0 = blockIdx.y * 256, col0 = blockIdx.x * 256;
    int tid = threadIdx.x, lane = tid & 63, wv = tid >> 6;
    int wr = wv >> 2, wc = wv & 3;

    const int srow = wv * 16 + (lane >> 2);
    const int scol = ((lane & 3) ^ ((lane >> 3) & 3)) * 8;
    const _Float16* gA0 = Ab + (size_t)(row0 + srow) * 1024 + scol;
    const _Float16* gA1 = gA0 + (size_t)128 * 1024;
    const _Float16* gB0 = Bb + (size_t)(col0 + srow) * 1024 + scol;
    const _Float16* gB1 = gB0 + (size_t)128 * 1024;

    const int rl = lane & 15;
    const int kq = (lane >> 4) * 8;
    const int kqa = kq ^ (((rl >> 1) & 3) << 3);  // read-side swizzle

    float4v acc[8][4] = {};
    half8 a[8], b[4];

    // Prologue: stage tiles 0,1,2 (12 gloads; oldest 4 = tile 0).
    STAGE_A(0, 0) STAGE_B(0, 0)
    STAGE_A(1, 1) STAGE_B(1, 1)
    STAGE_A(2, 2) STAGE_B(2, 2)

#pragma unroll 1
    for (int g = 0; g < 7; ++g) {  // tiles 4g..4g+3, stage 4g+3..4g+6
        int t = g * 4;
        TILE(0, 1, t + 3, 3, "vmcnt(8)")
        TILE(1, 1, t + 4, 0, "vmcnt(8)")
        TILE(2, 1, t + 5, 1, "vmcnt(8)")
        TILE(3, 1, t + 6, 2, "vmcnt(8)")
    }
    // Tiles 28..31 (t=28 stages tile 31).
    TILE(0, 1, 31, 3, "vmcnt(8)")
    TILE(1, 0, 0, 0, "vmcnt(8)")
    TILE(2, 0, 0, 0, "vmcnt(4)")
    TILE(3, 0, 0, 0, "vmcnt(0)")

    // Epilogue. C/D layout: col = lane&15, row = (lane>>4)*4 + reg  [m89]
#pragma unroll
    for (int m = 0; m < 8; m++) {
#pragma unroll
        for (int r = 0; r < 4; r++) {
            int row = row0 + wr * 128 + m * 16 + ((lane >> 4) << 2) + r;
            float add0 = 0.f, mu = 0.f, invs = 1.f, bet = 0.f;
            if constexpr (EPI == EP_F16B) add0 = bias[row];
            if constexpr (EPI == EP_FIN) {
                add0 = bc[row];
                mu = rmean[row];
                invs = gamma[row] * rsqrtf(rvar[row] + 1e-5f);
                bet = beta[row];
            }
#pragma unroll
            for (int n = 0; n < 4; n++) {
                int col = col0 + wc * 64 + n * 16 + (lane & 15);
                float v = acc[m][n][r];
                if constexpr (EPI == EP_F16B) {
                    ((_Float16*)Cp)[(size_t)z * sC + (size_t)row * 1024 + col] = (_Float16)(v + add0);
                } else if constexpr (EPI == EP_F32) {
                    ((float*)Cp)[(size_t)z * sC + (size_t)row * 1024 + col] = v;
                } else if constexpr (EPI == EP_F16) {
                    ((_Float16*)Cp)[(size_t)z * sC + (size_t)row * 1024 + col] = (_Float16)v;
                } else {
                    v += add0;
                    v = v >= 0.f ? v : 0.01f * v;
                    v = (v - mu) * invs + bet;
                    v += xres[(size_t)z * M2 + (size_t)row * 1024 + col];
                    ((float*)Cp)[(size_t)z * sC + (size_t)row * 1024 + col] = v;
                }
            }
        }
    }
}

// ---------------------------------------------------------------------------
extern "C" void kernel_launch(void* const* d_in, const int* in_sizes, int n_in,
                              void* d_out, int out_size, void* d_ws, size_t ws_size,
                              hipStream_t stream) {
    const float* x = (const float*)d_in[0];
    const float* Wf = (const float*)d_in[1];
    const float* bf = (const float*)d_in[2];
    const float* Wg = (const float*)d_in[3];
    const float* bg = (const float*)d_in[4];
    const float* Wh = (const float*)d_in[5];
    const float* bh = (const float*)d_in[6];
    const float* Wc = (const float*)d_in[7];
    const float* bc = (const float*)d_in[8];
    const float* gamma = (const float*)d_in[9];
    const float* beta = (const float*)d_in[10];
    const float* rmean = (const float*)d_in[11];
    const float* rvar = (const float*)d_in[12];

    // Fixed ws region: Wfgh f16 (6MB; slots F,G,CH) + WcH f16 (2MB) + bstack
    char* p = (char*)d_ws;
    _Float16* Wfgh = (_Float16*)p;
    p += (size_t)3 * M2 * 2;
    _Float16* WcH = (_Float16*)p;
    p += (size_t)M2 * 2;
    float* bstack = (float*)p;
    p += (size_t)3 * CD * 4;
    size_t fixed = (size_t)(p - (char*)d_ws);
    fixed = (fixed + 255) & ~(size_t)255;

    // Per-batch region: xT f16 (2MB, reused as attnT) + FGH f16 (6MB) +
    // ST f32 (4MB). 12 MiB per batch.
    size_t perB = (size_t)2 * M2 + (size_t)6 * M2 + (size_t)4 * M2;
    int nb = 16;
    while (nb > 1 && fixed + (size_t)nb * perB > ws_size) nb >>= 1;

    char* q = (char*)d_ws + fixed;

    {
        int total = 4 * M2 + 3 * CD;
        prep_weights<<<dim3((total + 255) / 256), dim3(256), 0, stream>>>(
            Wf, Wg, Wh, Wc, bf, bg, bh, Wfgh, WcH, bstack);
    }
    // Fold Wc into the h-projection:  Wch = Wc . Wh,  bch = Wc . bh.
    // WhT (f16) goes in the per-batch scratch (dead before the batch loop).
    {
        _Float16* WhT = (_Float16*)q;
        transpose_x<<<dim3(32, 32, 1), dim3(32, 8), 0, stream>>>(Wh, WhT, 0);
        gemv_bch<<<dim3(256), dim3(256), 0, stream>>>(Wc, bh, bstack + 2 * CD);
        gemm128<<<dim3(8, 8), dim3(256), 0, stream>>>(WcH, WhT, Wfgh + (size_t)2 * M2);
    }

    for (int b0 = 0; b0 < 16; b0 += nb) {
        _Float16* xT = (_Float16*)q;
        _Float16* FGH = (_Float16*)(q + (size_t)nb * 2 * M2);
        float* ST = (float*)(q + (size_t)nb * 8 * M2);
        _Float16* attnT = xT;  // xT dead after proj GEMM

        // xT[z][n][k] = x[b0+z][k][n]
        transpose_x<<<dim3(32, 32, nb), dim3(32, 8), 0, stream>>>(x, xT, b0);
        // FGH[z] (3072x1024) = [Wf;Wg;Wch] . xT[z]^T + [bf;bg;bch]
        gemm_nt<EP_F16B><<<dim3(4, 12, nb), dim3(512), 0, stream>>>(
            Wfgh, 0, xT, M2, FGH, (int64_t)3 * M2, bstack,
            nullptr, nullptr, nullptr, nullptr, nullptr, nullptr);
        // ST[z][d][c] = sum_n G[d][n] F[c][n]   (= scores[c][d])
        gemm_nt<EP_F32><<<dim3(4, 4, nb), dim3(512), 0, stream>>>(
            FGH + M2, (int64_t)3 * M2, FGH, (int64_t)3 * M2, ST, M2,
            nullptr, nullptr, nullptr, nullptr, nullptr, nullptr, nullptr);
        // attnT[z][d][c] = softmax over c of ST[z][d][:]
        softmax_col<<<dim3(1024, nb), dim3(256), 0, stream>>>(ST, attnT);
        // out[b][o][d] = BN(leaky(sum_n CH[o][n] attnT[d][n] + bc)) + x
        gemm_nt<EP_FIN><<<dim3(4, 4, nb), dim3(512), 0, stream>>>(
            FGH + (size_t)2 * M2, (int64_t)3 * M2, attnT, M2,
            (float*)d_out + (size_t)b0 * M2, M2,
            nullptr, bc, gamma, beta, rmean, rvar, x + (size_t)b0 * M2);
    }
}